// Round 17
// baseline (277.653 us; speedup 1.0000x reference)
//
#include <hip/hip_runtime.h>
#include <hip/hip_bf16.h>
#include <math.h>

#define S_TOT 20000
#define Q_TOT 32
#define N_TOT 200000
#define T_MAX 30
#define G_TOT 64
#define D_IN 300
#define H_DIM 256
#define D_SV 64
#define D_LANG 64
#define D_FUSE 128
#define D_CAT 67
#define FW_LD 131
#define SCHUNK 32
#define NBLK3 (S_TOT / SCHUNK)   // 625
#define SENT64 0xFFFFFFFFFFFFFFFFull
#define PCHUNK 8
#define PTILES 79                // ceil(625/8)
#define HG_ELEMS (30 * Q_TOT * H_DIM)
#define MEGA_GRID 256

// syncs ints (2048): [0..31] interG | [32..63] unionG | [64] t_out | [65] gtickL | [66] gtick
// qdone[q]=128+32q | qtick[q]=129+32q | tfc[c]=1152+32c (c<8)
// langc flags 1408+32i | best flags 1664+32i (i<8)
#define SYNCS_N 2048

__device__ __forceinline__ float sigmoidf_(float x) { return 1.0f / (1.0f + expf(-x)); }
__device__ __forceinline__ unsigned long long pack2(float a, float b) {
    return ((unsigned long long)__float_as_uint(b) << 32) | (unsigned long long)__float_as_uint(a);
}

// ---------------------------------------------------------------- k_init: transposes + hg sentinel + syncs
__global__ __launch_bounds__(128) void k_init(const float* __restrict__ fuse_w,
                                              const float* __restrict__ sqz_w1,
                                              const float* __restrict__ sqz_w2,
                                              const float* __restrict__ heat_w,
                                              float* __restrict__ fwt,
                                              float* __restrict__ w1t,
                                              float* __restrict__ w2t,
                                              float* __restrict__ wdr,
                                              float* __restrict__ hg,
                                              int* __restrict__ syncs) {
    const int tid = threadIdx.x;
    if (blockIdx.x == 0) {
        for (int i = tid; i < FW_LD * D_FUSE; i += 128)
            fwt[(i % FW_LD) * D_FUSE + (i / FW_LD)] = fuse_w[i];
        for (int i = tid; i < D_LANG * H_DIM; i += 128)
            w1t[(i & 255) * D_LANG + (i >> 8)] = sqz_w1[i];
        for (int i = tid; i < D_LANG * D_LANG; i += 128)
            w2t[(i & 63) * D_LANG + (i >> 6)] = sqz_w2[i];
        if (tid < D_FUSE) wdr[tid] = heat_w[D_FUSE + tid] - heat_w[tid];
    } else {
        const int fb = blockIdx.x - 1;                  // 0..7
        const int per4 = HG_ELEMS / 4 / 8;              // 7680
        float4* dst = (float4*)hg + fb * per4;
        const float4 sv = make_float4(__uint_as_float(0xFFFFFFFFu), __uint_as_float(0xFFFFFFFFu),
                                      __uint_as_float(0xFFFFFFFFu), __uint_as_float(0xFFFFFFFFu));
        for (int i = tid; i < per4; i += 128) dst[i] = sv;
        if (fb == 0) for (int i = tid; i < SYNCS_N; i += 128) syncs[i] = 0;
    }
}

// ---------------------------------------------------------------- k_mega: gi | gru | lang | fuse | argmax | out
// 256 blocks x 384 thr, 111 KB LDS -> exactly 1 block/CU, ALL blocks co-resident (no deadlock).
__global__ __launch_bounds__(384, 1) void k_mega(
    const float* __restrict__ lang_feat,
    const float* __restrict__ w_ih, const float* __restrict__ b_ih,
    const float* __restrict__ w_hh, const float* __restrict__ b_hh,
    const int* __restrict__ lang_len,
    float* __restrict__ hg, float* __restrict__ hbuf,
    const float* __restrict__ w1t, const float* __restrict__ b1,
    const float* __restrict__ w2t, const float* __restrict__ b2,
    const float* __restrict__ fwt, const float* __restrict__ fuse_b,
    float* __restrict__ langc,
    const float* __restrict__ feat, const float* __restrict__ coords,
    const int* __restrict__ grps, const float* __restrict__ wdr_g,
    const float* __restrict__ heat_b,
    float* __restrict__ grp_part, int* __restrict__ cnt_part,
    float* __restrict__ grp2, int* __restrict__ cnt2,
    int* __restrict__ best,
    const int* __restrict__ supervox, const int* __restrict__ gt,
    float* __restrict__ out, int* __restrict__ syncs)
{
    const int tid = threadIdx.x, bid = blockIdx.x;
    const int q = bid >> 3, b = bid & 7;
    int len = lang_len[q]; if (len > T_MAX) len = T_MAX; if (len < 1) len = 1;

    __shared__ __align__(16) unsigned char SM[111360];
    float* WL   = (float*)SM;                     // 96*256 recurrent weights (swizzled)
    float* XL   = (float*)SM;                     // gi staging: x[30][104]
    float* WcL  = (float*)(SM + 12480);           // gi staging: W[96][104]
    float* HLQ  = (float*)(SM + 98304);           // 4*68
    float* GHL  = (float*)(SM + 99392);           // 96
    float* GIL  = (float*)(SM + 99776);           // 30*96 (also lang scratch)
    float* SVIN = (float*)SM;                     // tail: [32][68]
    float* SVP  = (float*)(SM + 8704);            // [32][132]
    float* SCOREL = (float*)(SM + 25600);         // [32][32]
    int*   GRPSL  = (int*)(SM + 29696);           // 32
    float* PS   = (float*)(SM + 29824);           // [4][64]
    int*   PC   = (int*)(SM + 30848);             // [4][64]
    float* SC   = (float*)(SM + 31872);           // 64
    int*   BLs  = (int*)(SM + 32128);             // 32
    int*   GMs  = (int*)(SM + 32256);             // 64
    int*   BIS  = (int*)(SM + 32512);             // 32
    int*   BUS  = (int*)(SM + 32640);             // 32
    __shared__ int sflag1, sflag2;

    // ================= phase GI (inline): gil = x[q] @ W_ih[slice]^T + b_ih
    const int r96 = tid >> 2, tg = tid & 3;
    const int growI = ((r96 >> 5) << 8) + (b << 5) + (r96 & 31);
    float gacc[8];
    #pragma unroll
    for (int j = 0; j < 8; ++j) gacc[j] = 0.f;
    for (int kc = 0; kc < 3; ++kc) {
        const int k0 = kc * 100;
        for (int i = tid; i < 3000; i += 384) {
            const int t = i / 100, k = i - 100 * t;
            XL[t * 104 + k] = lang_feat[(q * T_MAX + t) * D_IN + k0 + k];
        }
        for (int i = tid; i < 9600; i += 384) {
            const int rr = i / 100, k = i - 100 * rr;
            WcL[rr * 104 + k] =
                w_ih[(size_t)(((rr >> 5) << 8) + (b << 5) + (rr & 31)) * D_IN + k0 + k];
        }
        __syncthreads();
        for (int k4 = 0; k4 < 25; ++k4) {
            const float4 wv = *(const float4*)&WcL[r96 * 104 + 4 * k4];
            #pragma unroll
            for (int j = 0; j < 8; ++j) {
                const int t = tg + 4 * j;
                if (t < 30) {
                    const float4 xv = *(const float4*)&XL[t * 104 + 4 * k4];
                    gacc[j] = fmaf(wv.x, xv.x, fmaf(wv.y, xv.y,
                              fmaf(wv.z, xv.z, fmaf(wv.w, xv.w, gacc[j]))));
                }
            }
        }
        __syncthreads();
    }
    {
        const float bih = b_ih[growI];
        #pragma unroll
        for (int j = 0; j < 8; ++j) {
            const int t = tg + 4 * j;
            if (t < 30) GIL[t * 96 + r96] = gacc[j] + bih;
        }
    }
    // stage recurrent weights swizzled (overwrites gi staging region)
    {
        const float4* src4 = (const float4*)w_hh;
        float4* dst4 = (float4*)WL;
        for (int i = tid; i < 96 * 64; i += 384) {
            const int rr = i >> 6, c = i & 63;
            const int grow = ((rr >> 5) << 8) + (b << 5) + (rr & 31);
            dst4[rr * 64 + (c ^ (rr & 7))] = src4[grow * 64 + c];
        }
    }
    __syncthreads();

    // ================= phase GRU (R11 structure)
    float hfin = 0.f;
    {
        float hnew = 0.f;
        if (tid < 32) {
            const float bhr = b_hh[(b << 5) + tid];
            const float bhz = b_hh[H_DIM + (b << 5) + tid];
            const float bhn = b_hh[2 * H_DIM + (b << 5) + tid];
            const float r = sigmoidf_(GIL[tid] + bhr);
            const float z = sigmoidf_(GIL[32 + tid] + bhz);
            const float n = tanhf(GIL[64 + tid] + r * bhn);
            hnew = (1.f - z) * n;
            if (len == 1) hfin = hnew;
        }
        if (tid < 64 && len > 1) {
            const float a0 = __shfl(hnew, 2 * (tid & 15));
            const float a1 = __shfl(hnew, 2 * (tid & 15) + 1);
            if (tid < 16) {
                unsigned long long* dst = (unsigned long long*)(hg + q * H_DIM + (b << 5));
                __hip_atomic_store(dst + tid, pack2(a0, a1), __ATOMIC_RELAXED, __HIP_MEMORY_SCOPE_AGENT);
            }
        }
    }
    {
        const int row = tid >> 2, ql = tid & 3;
        const float bh = b_hh[((row >> 5) << 8) + (b << 5) + (row & 31)];
        const int rx = row & 7;
        const float4* wrow4 = (const float4*)WL + row * 64;
        const int cbase = ql << 4;
        for (int t = 1; t < len; ++t) {
            if (tid < 128) {
                const unsigned long long* src =
                    (const unsigned long long*)(hg + (size_t)(t - 1) * (Q_TOT * H_DIM) + q * H_DIM);
                unsigned long long v;
                while ((v = __hip_atomic_load(src + tid, __ATOMIC_RELAXED,
                                              __HIP_MEMORY_SCOPE_AGENT)) == SENT64)
                    __builtin_amdgcn_s_sleep(1);
                const int k = 2 * tid;
                const int o = (k >> 6) * 68 + (k & 63);
                HLQ[o]     = __uint_as_float((unsigned)(v & 0xffffffffu));
                HLQ[o + 1] = __uint_as_float((unsigned)(v >> 32));
            }
            __syncthreads();
            float hold = 0.f;
            if (tid < 32) { const int k = (b << 5) + tid; hold = HLQ[(k >> 6) * 68 + (k & 63)]; }
            const float4* h4 = (const float4*)(HLQ + ql * 68);
            float ax = 0.f, ay = 0.f, az = 0.f, aw = 0.f;
            #pragma unroll
            for (int i = 0; i < 16; ++i) {
                const float4 wv = wrow4[(cbase + i) ^ rx];
                const float4 hv = h4[i];
                ax = fmaf(wv.x, hv.x, ax);
                ay = fmaf(wv.y, hv.y, ay);
                az = fmaf(wv.z, hv.z, az);
                aw = fmaf(wv.w, hv.w, aw);
            }
            float s = (ax + ay) + (az + aw);
            s += __shfl_xor(s, 1);
            s += __shfl_xor(s, 2);
            if (ql == 0) GHL[row] = s + bh;
            __syncthreads();
            float hnew = 0.f;
            if (tid < 32) {
                const float* gt_ = GIL + t * 96;
                const float r = sigmoidf_(gt_[tid] + GHL[tid]);
                const float z = sigmoidf_(gt_[32 + tid] + GHL[32 + tid]);
                const float n = tanhf(gt_[64 + tid] + r * GHL[64 + tid]);
                hnew = (1.f - z) * n + z * hold;
                if (t == len - 1) hfin = hnew;
            }
            if (tid < 64 && t < len - 1) {
                const float a0 = __shfl(hnew, 2 * (tid & 15));
                const float a1 = __shfl(hnew, 2 * (tid & 15) + 1);
                if (tid < 16) {
                    unsigned long long* dst =
                        (unsigned long long*)(hg + (size_t)t * (Q_TOT * H_DIM) + q * H_DIM + (b << 5));
                    __hip_atomic_store(dst + tid, pack2(a0, a1), __ATOMIC_RELAXED, __HIP_MEMORY_SCOPE_AGENT);
                }
            }
        }
    }
    if (tid < 32)
        __hip_atomic_store(&hbuf[q * H_DIM + (b << 5) + tid], hfin,
                           __ATOMIC_RELAXED, __HIP_MEMORY_SCOPE_AGENT);
    asm volatile("s_waitcnt vmcnt(0)" ::: "memory");
    __syncthreads();
    if (tid == 0)
        __hip_atomic_fetch_add(&syncs[128 + 32 * q], 1, __ATOMIC_RELAXED, __HIP_MEMORY_SCOPE_AGENT);

    // ================= phase L: lang head (b==0 blocks only)
    if (b == 0) {
        if (tid == 0) {
            while (__hip_atomic_load(&syncs[128 + 32 * q], __ATOMIC_RELAXED, __HIP_MEMORY_SCOPE_AGENT) < 8)
                __builtin_amdgcn_s_sleep(2);
        }
        __syncthreads();
        float* hql = GIL;
        float* t1l = GIL + 256;
        float* lgl = GIL + 320;
        if (tid < H_DIM)
            hql[tid] = __hip_atomic_load(&hbuf[q * H_DIM + tid], __ATOMIC_RELAXED, __HIP_MEMORY_SCOPE_AGENT);
        __syncthreads();
        if (tid < 256) {
            const int c = tid >> 2, qq = tid & 3;
            float a = 0.f;
            #pragma unroll 8
            for (int j = 0; j < 64; ++j) {
                const int k = (qq << 6) + j;
                a = fmaf(w1t[k * D_LANG + c], hql[k], a);
            }
            a += __shfl_xor(a, 1);
            a += __shfl_xor(a, 2);
            if (qq == 0) t1l[c] = fmaxf(a + b1[c], 0.f);
        }
        __syncthreads();
        if (tid < 256) {
            const int c = tid >> 2, qq = tid & 3;
            float a = 0.f;
            #pragma unroll
            for (int j = 0; j < 16; ++j) {
                const int k = (qq << 4) + j;
                a = fmaf(w2t[k * D_LANG + c], t1l[k], a);
            }
            a += __shfl_xor(a, 1);
            a += __shfl_xor(a, 2);
            if (qq == 0) lgl[c] = a + b2[c];
        }
        __syncthreads();
        if (tid < 256) {
            const int d = tid >> 1, hh = tid & 1;
            float a = 0.f;
            #pragma unroll 8
            for (int j = 0; j < 32; ++j) {
                const int k = (hh << 5) + j;
                a = fmaf(fwt[(D_CAT + k) * D_FUSE + d], lgl[k], a);
            }
            a += __shfl_xor(a, 1);
            if (hh == 0)
                __hip_atomic_store(&langc[q * D_FUSE + d], a + fuse_b[d],
                                   __ATOMIC_RELAXED, __HIP_MEMORY_SCOPE_AGENT);
        }
        asm volatile("s_waitcnt vmcnt(0)" ::: "memory");
        __syncthreads();
        if (tid == 0) {
            const int old = __hip_atomic_fetch_add(&syncs[65], 1, __ATOMIC_RELAXED, __HIP_MEMORY_SCOPE_AGENT);
            if (old == Q_TOT - 1) {
                #pragma unroll
                for (int f = 0; f < 8; ++f)
                    __hip_atomic_store(&syncs[1408 + 32 * f], 1, __ATOMIC_RELAXED, __HIP_MEMORY_SCOPE_AGENT);
            }
        }
    }
    // all blocks: wait langc-ready
    if (tid == 0) {
        int* fl = &syncs[1408 + 32 * (bid & 7)];
        while (__hip_atomic_load(fl, __ATOMIC_RELAXED, __HIP_MEMORY_SCOPE_AGENT) == 0)
            __builtin_amdgcn_s_sleep(8);
    }
    __syncthreads();

    // ================= phase F: fused score + group partials (tiles bid, bid+256, bid+512)
    {
        const int dsl = tid & 7, qf = tid >> 3;      // valid for tid<256
        float lc[16], wdr[16];
        if (tid < 256) {
            #pragma unroll
            for (int i = 0; i < 16; ++i) {
                const int d = dsl * 16 + i;
                lc[i]  = langc[qf * D_FUSE + d];
                wdr[i] = wdr_g[d];
            }
        }
        const float hbd = heat_b[1] - heat_b[0];

        for (int tile = bid; tile < NBLK3; tile += MEGA_GRID) {
            const int s0 = tile * SCHUNK;
            __syncthreads();
            for (int i = tid; i < SCHUNK * D_SV; i += 384) {
                const int r = i >> 6, c = i & 63;
                SVIN[r * 68 + c] = feat[(s0 + r) * D_SV + c];
            }
            if (tid < SCHUNK * 3) { const int r = tid / 3, c = tid % 3; SVIN[r * 68 + D_SV + c] = coords[(s0 + r) * 3 + c]; }
            if (tid < SCHUNK) GRPSL[tid] = grps[s0 + tid];
            __syncthreads();
            if (tid < 256) {
                const int d = tid & 127, sl0 = tid >> 7;
                float acc[16];
                #pragma unroll
                for (int i = 0; i < 16; ++i) acc[i] = 0.f;
                for (int k4 = 0; k4 < 16; ++k4) {
                    const float w0 = fwt[(4 * k4 + 0) * D_FUSE + d];
                    const float w1 = fwt[(4 * k4 + 1) * D_FUSE + d];
                    const float w2 = fwt[(4 * k4 + 2) * D_FUSE + d];
                    const float w3 = fwt[(4 * k4 + 3) * D_FUSE + d];
                    #pragma unroll
                    for (int i = 0; i < 16; ++i) {
                        const float4 xv = *(const float4*)&SVIN[(sl0 + 2 * i) * 68 + 4 * k4];
                        acc[i] = fmaf(xv.x, w0, fmaf(xv.y, w1, fmaf(xv.z, w2, fmaf(xv.w, w3, acc[i]))));
                    }
                }
                for (int k = 64; k < D_CAT; ++k) {
                    const float wv = fwt[k * D_FUSE + d];
                    #pragma unroll
                    for (int i = 0; i < 16; ++i)
                        acc[i] = fmaf(SVIN[(sl0 + 2 * i) * 68 + k], wv, acc[i]);
                }
                #pragma unroll
                for (int i = 0; i < 16; ++i) SVP[(sl0 + 2 * i) * 132 + d] = acc[i];
            }
            __syncthreads();
            if (tid < 256) {
                for (int sl = 0; sl < SCHUNK; ++sl) {
                    const float4* sv4 = (const float4*)(&SVP[sl * 132 + dsl * 16]);
                    float part = 0.f;
                    #pragma unroll
                    for (int j = 0; j < 4; ++j) {
                        const float4 v = sv4[j];
                        part = fmaf(fmaxf(v.x + lc[4*j+0], 0.f), wdr[4*j+0], part);
                        part = fmaf(fmaxf(v.y + lc[4*j+1], 0.f), wdr[4*j+1], part);
                        part = fmaf(fmaxf(v.z + lc[4*j+2], 0.f), wdr[4*j+2], part);
                        part = fmaf(fmaxf(v.w + lc[4*j+3], 0.f), wdr[4*j+3], part);
                    }
                    part += __shfl_xor(part, 1);
                    part += __shfl_xor(part, 2);
                    part += __shfl_xor(part, 4);
                    if (dsl == 0) SCOREL[sl * 32 + qf] = sigmoidf_(part + hbd);
                }
            }
            __syncthreads();
            for (int cell = tid; cell < Q_TOT * G_TOT; cell += 384) {
                const int qq = cell >> 6, g = cell & 63;
                float sum = 0.f;
                #pragma unroll
                for (int sl = 0; sl < SCHUNK; ++sl)
                    sum += (GRPSL[sl] == g) ? SCOREL[sl * 32 + qq] : 0.f;
                __hip_atomic_store(&grp_part[tile * (Q_TOT * G_TOT) + cell], sum,
                                   __ATOMIC_RELAXED, __HIP_MEMORY_SCOPE_AGENT);
                if (cell < G_TOT) {
                    int c = 0;
                    #pragma unroll
                    for (int sl = 0; sl < SCHUNK; ++sl) c += (GRPSL[sl] == g);
                    __hip_atomic_store(&cnt_part[tile * G_TOT + g], c,
                                       __ATOMIC_RELAXED, __HIP_MEMORY_SCOPE_AGENT);
                }
            }
            asm volatile("s_waitcnt vmcnt(0)" ::: "memory");
            __syncthreads();
            if (tid == 0)
                __hip_atomic_fetch_add(&syncs[1152 + 32 * (tile / PTILES)], 1,
                                       __ATOMIC_RELAXED, __HIP_MEMORY_SCOPE_AGENT);
        }
    }

    // ================= phase A: two-stage reduction + argmax (q = bid&31, c = bid>>5)
    {
        const int qa = bid & 31, ca = bid >> 5;       // ca in 0..7
        const int b0 = ca * PTILES;
        int b1 = b0 + PTILES; if (b1 > NBLK3) b1 = NBLK3;
        if (tid == 0) {
            int* tc = &syncs[1152 + 32 * ca];
            const int tgt = b1 - b0;
            while (__hip_atomic_load(tc, __ATOMIC_RELAXED, __HIP_MEMORY_SCOPE_AGENT) < tgt)
                __builtin_amdgcn_s_sleep(4);
        }
        __syncthreads();
        if (tid < 256) {
            const int bq = tid >> 6, g = tid & 63;
            float acc = 0.f; int cacc = 0;
            for (int bb = b0 + bq; bb < b1; bb += 4) {
                acc  += grp_part[bb * (Q_TOT * G_TOT) + qa * G_TOT + g];
                cacc += cnt_part[bb * G_TOT + g];
            }
            PS[bq * 64 + g] = acc; PC[bq * 64 + g] = cacc;
        }
        __syncthreads();
        if (tid < G_TOT) {
            const float s = ((PS[tid] + PS[64 + tid]) + PS[128 + tid]) + PS[192 + tid];
            const int  cc = ((PC[tid] + PC[64 + tid]) + PC[128 + tid]) + PC[192 + tid];
            __hip_atomic_store(&grp2[(ca * Q_TOT + qa) * G_TOT + tid], s,
                               __ATOMIC_RELAXED, __HIP_MEMORY_SCOPE_AGENT);
            __hip_atomic_store(&cnt2[(ca * Q_TOT + qa) * G_TOT + tid], cc,
                               __ATOMIC_RELAXED, __HIP_MEMORY_SCOPE_AGENT);
        }
        asm volatile("s_waitcnt vmcnt(0)" ::: "memory");
        if (tid == 0) {
            const int old = __hip_atomic_fetch_add(&syncs[129 + 32 * qa], 1,
                                                   __ATOMIC_RELAXED, __HIP_MEMORY_SCOPE_AGENT);
            sflag1 = (old == PCHUNK - 1) ? 1 : 0;
        }
        __syncthreads();
        if (sflag1) {
            if (tid < G_TOT) {
                float s = 0.f; int cc = 0;
                #pragma unroll
                for (int c2 = 0; c2 < PCHUNK; ++c2) {
                    s  += grp2[(c2 * Q_TOT + qa) * G_TOT + tid];
                    cc += cnt2[(c2 * Q_TOT + qa) * G_TOT + tid];
                }
                SC[tid] = s / (float)cc;
            }
            __syncthreads();
            if (tid == 0) {
                float bv = SC[0]; int bi = 0;
                for (int g2 = 1; g2 < G_TOT; ++g2) if (SC[g2] > bv) { bv = SC[g2]; bi = g2; }
                __hip_atomic_store(&best[qa], bi, __ATOMIC_RELAXED, __HIP_MEMORY_SCOPE_AGENT);
                asm volatile("s_waitcnt vmcnt(0)" ::: "memory");
                const int old = __hip_atomic_fetch_add(&syncs[66], 1, __ATOMIC_RELAXED, __HIP_MEMORY_SCOPE_AGENT);
                if (old == Q_TOT - 1) {
                    #pragma unroll
                    for (int f = 0; f < 8; ++f)
                        __hip_atomic_store(&syncs[1664 + 32 * f], 1,
                                           __ATOMIC_RELAXED, __HIP_MEMORY_SCOPE_AGENT);
                }
            }
        }
    }

    // wait best-ready
    if (tid == 0) {
        int* fl = &syncs[1664 + 32 * (bid & 7)];
        while (__hip_atomic_load(fl, __ATOMIC_RELAXED, __HIP_MEMORY_SCOPE_AGENT) == 0)
            __builtin_amdgcn_s_sleep(16);
    }
    __syncthreads();
    if (tid < Q_TOT) BLs[tid] = best[tid];
    __syncthreads();
    if (tid < G_TOT) {
        int m = 0;
        #pragma unroll
        for (int qq = 0; qq < Q_TOT; ++qq) m |= (BLs[qq] == tid) ? (1 << qq) : 0;
        GMs[tid] = m;
    }
    __syncthreads();

    // ================= phase O: obj_pts + inter/union + iou
    {
        const int gidx = bid * 384 + tid;
        const int q4 = (gidx & 7) * 4;
        const int nstride = (MEGA_GRID * 384) >> 3;   // 12288
        int a0 = 0, a1 = 0, a2 = 0, a3 = 0;
        int u0 = 0, u1 = 0, u2 = 0, u3 = 0;
        for (int n = gidx >> 3; n < N_TOT; n += nstride) {
            const int m = GMs[grps[supervox[n]]];
            const int4 g4 = *(const int4*)&gt[n * Q_TOT + q4];
            const int o0 = (m >> (q4 + 0)) & 1;
            const int o1 = (m >> (q4 + 1)) & 1;
            const int o2 = (m >> (q4 + 2)) & 1;
            const int o3 = (m >> (q4 + 3)) & 1;
            *(float4*)&out[n * Q_TOT + q4] =
                make_float4((float)o0, (float)o1, (float)o2, (float)o3);
            a0 += o0 & g4.x; u0 += o0 | g4.x;
            a1 += o1 & g4.y; u1 += o1 | g4.y;
            a2 += o2 & g4.z; u2 += o2 | g4.z;
            a3 += o3 & g4.w; u3 += o3 | g4.w;
        }
        if (tid < Q_TOT) { BIS[tid] = 0; BUS[tid] = 0; }
        __syncthreads();
        atomicAdd(&BIS[q4 + 0], a0); atomicAdd(&BUS[q4 + 0], u0);
        atomicAdd(&BIS[q4 + 1], a1); atomicAdd(&BUS[q4 + 1], u1);
        atomicAdd(&BIS[q4 + 2], a2); atomicAdd(&BUS[q4 + 2], u2);
        atomicAdd(&BIS[q4 + 3], a3); atomicAdd(&BUS[q4 + 3], u3);
        __syncthreads();
        if (tid < Q_TOT) { atomicAdd(&syncs[tid], BIS[tid]); atomicAdd(&syncs[32 + tid], BUS[tid]); }
        asm volatile("s_waitcnt vmcnt(0)" ::: "memory");
        if (tid == 0) {
            const int old = __hip_atomic_fetch_add(&syncs[64], 1, __ATOMIC_RELAXED, __HIP_MEMORY_SCOPE_AGENT);
            sflag2 = (old == MEGA_GRID - 1) ? 1 : 0;
        }
        __syncthreads();
        if (sflag2 && tid < Q_TOT) {
            const int iv = __hip_atomic_load(&syncs[tid], __ATOMIC_RELAXED, __HIP_MEMORY_SCOPE_AGENT);
            const int uv = __hip_atomic_load(&syncs[32 + tid], __ATOMIC_RELAXED, __HIP_MEMORY_SCOPE_AGENT);
            out[(size_t)N_TOT * Q_TOT + tid] = (float)iv / ((float)uv + 1e-5f);
        }
    }
}

extern "C" void kernel_launch(void* const* d_in, const int* in_sizes, int n_in,
                              void* d_out, int out_size, void* d_ws, size_t ws_size,
                              hipStream_t stream) {
    const float* lang_feat = (const float*)d_in[0];
    const float* feat      = (const float*)d_in[1];
    const float* coords    = (const float*)d_in[2];
    const int*   lang_len  = (const int*)d_in[3];
    const int*   grps      = (const int*)d_in[4];
    const int*   supervox  = (const int*)d_in[5];
    const int*   gt        = (const int*)d_in[6];
    const float* w_ih      = (const float*)d_in[7];
    const float* w_hh      = (const float*)d_in[8];
    const float* b_ih      = (const float*)d_in[9];
    const float* b_hh      = (const float*)d_in[10];
    const float* sqz_w1    = (const float*)d_in[11];
    const float* sqz_b1    = (const float*)d_in[12];
    const float* sqz_w2    = (const float*)d_in[13];
    const float* sqz_b2    = (const float*)d_in[14];
    const float* fuse_w    = (const float*)d_in[15];
    const float* fuse_b    = (const float*)d_in[16];
    const float* heat_w    = (const float*)d_in[17];
    const float* heat_b    = (const float*)d_in[18];
    float* out = (float*)d_out;

    float* hbuf     = (float*)d_ws;                       // 8192
    float* langc    = hbuf + 8192;                        // 4096
    float* grp_part = langc + 4096;                       // 1280000
    int*   cnt_part = (int*)(grp_part + NBLK3 * 2048);    // 40000
    int*   best     = cnt_part + NBLK3 * 64;              // 32
    int*   syncs    = best + 32;                          // 2048
    float* hg       = (float*)(syncs + SYNCS_N);          // 245760
    float* fwt      = hg + HG_ELEMS;                      // 16768
    float* w1t      = fwt + FW_LD * D_FUSE;               // 16384
    float* w2t      = w1t + H_DIM * D_LANG;               // 4096
    float* wdr      = w2t + D_LANG * D_LANG;              // 128
    float* grp2     = wdr + 128;                          // 16384 used
    int*   cnt2     = (int*)(grp2 + PCHUNK * Q_TOT * G_TOT); // 16384

    k_init<<<9, 128, 0, stream>>>(fuse_w, sqz_w1, sqz_w2, heat_w,
                                  fwt, w1t, w2t, wdr, hg, syncs);
    k_mega<<<MEGA_GRID, 384, 0, stream>>>(lang_feat, w_ih, b_ih, w_hh, b_hh, lang_len,
                                          hg, hbuf, w1t, sqz_b1, w2t, sqz_b2, fwt, fuse_b, langc,
                                          feat, coords, grps, wdr, heat_b,
                                          grp_part, cnt_part, grp2, cnt2, best,
                                          supervox, gt, out, syncs);
}

// Round 18
// 206.611 us; speedup vs baseline: 1.3438x; 1.3438x over previous
//
#include <hip/hip_runtime.h>
#include <hip/hip_bf16.h>
#include <math.h>

#define S_TOT 20000
#define Q_TOT 32
#define N_TOT 200000
#define T_MAX 30
#define G_TOT 64
#define D_IN 300
#define H_DIM 256
#define D_SV 64
#define D_LANG 64
#define D_FUSE 128
#define D_CAT 67
#define FW_LD 131
#define SCHUNK 32
#define NBLK3 (S_TOT / SCHUNK)   // 625
#define SENT64 0xFFFFFFFFFFFFFFFFull
#define PCHUNK 16
#define PTILES 40
#define TAIL_GRID 1024

// k_gi GEMM tiling
#define GI_MT 32
#define GI_NT 64
#define GI_KC 100
#define GI_NB 12
#define GI_GRID (30 * GI_NB)     // 360
#define HG_ELEMS (30 * Q_TOT * H_DIM)

// syncs ints (line-spaced hot counters):
// [0..31] interG | [32..63] unionG | [64] t_out | [65] gtick
// [66..97] qdone (gru) | [98..129] qtick
// [160+32c] tfc chunk tickets (c=0..15) | [672+32i] doneflag (i=0..7)
#define SYNCS_N 1024

__device__ __forceinline__ float sigmoidf_(float x) { return 1.0f / (1.0f + expf(-x)); }
__device__ __forceinline__ unsigned long long pack2(float a, float b) {
    return ((unsigned long long)__float_as_uint(b) << 32) | (unsigned long long)__float_as_uint(a);
}

// ---------------------------------------------------------------- k_gi
__global__ __launch_bounds__(128) void k_gi(const float* __restrict__ lang_feat,
                                            const float* __restrict__ w_ih,
                                            const float* __restrict__ b_ih,
                                            const float* __restrict__ fuse_w,
                                            const float* __restrict__ sqz_w1,
                                            const float* __restrict__ sqz_w2,
                                            const float* __restrict__ heat_w,
                                            float* __restrict__ gi,
                                            float* __restrict__ fwt,
                                            float* __restrict__ w1t,
                                            float* __restrict__ w2t,
                                            float* __restrict__ wdr,
                                            float* __restrict__ hg,
                                            int* __restrict__ syncs) {
    const int tid = threadIdx.x;
    if (blockIdx.x >= GI_GRID) {
        const int xb = blockIdx.x - GI_GRID;
        if (xb == 0) {
            for (int i = tid; i < FW_LD * D_FUSE; i += 128)
                fwt[(i % FW_LD) * D_FUSE + (i / FW_LD)] = fuse_w[i];
            for (int i = tid; i < D_LANG * H_DIM; i += 128)
                w1t[(i & 255) * D_LANG + (i >> 8)] = sqz_w1[i];
            for (int i = tid; i < D_LANG * D_LANG; i += 128)
                w2t[(i & 63) * D_LANG + (i >> 6)] = sqz_w2[i];
            if (tid < D_FUSE) wdr[tid] = heat_w[D_FUSE + tid] - heat_w[tid];
        } else {
            const int fb = xb - 1;                        // 0..7
            const int per4 = HG_ELEMS / 4 / 8;
            float4* dst = (float4*)hg + fb * per4;
            const float4 sv = make_float4(__uint_as_float(0xFFFFFFFFu), __uint_as_float(0xFFFFFFFFu),
                                          __uint_as_float(0xFFFFFFFFu), __uint_as_float(0xFFFFFFFFu));
            for (int i = tid; i < per4; i += 128) dst[i] = sv;
            if (fb == 0) for (int i = tid; i < SYNCS_N; i += 128) syncs[i] = 0;
        }
        return;
    }
    __shared__ float x_l[GI_KC][GI_MT + 1];
    __shared__ float w_l[GI_KC][GI_NT + 1];
    const int mb = blockIdx.x / GI_NB, nb = blockIdx.x % GI_NB;
    const int m0 = mb * GI_MT, n0 = nb * GI_NT;
    const int tq4 = (tid >> 4) * 4, jq4 = (tid & 15) * 4;

    float acc[4][4];
    #pragma unroll
    for (int i = 0; i < 4; ++i)
        #pragma unroll
        for (int j = 0; j < 4; ++j) acc[i][j] = 0.f;

    for (int kc = 0; kc < 3; ++kc) {
        const int k0 = kc * GI_KC;
        for (int i = tid; i < GI_MT * GI_KC; i += 128) {
            const int r = i / GI_KC, k = i % GI_KC;
            const int row = m0 + r, q = row / T_MAX, t = row - q * T_MAX;
            x_l[k][r] = lang_feat[(q * T_MAX + t) * D_IN + k0 + k];
        }
        for (int i = tid; i < GI_NT * GI_KC; i += 128) {
            const int r = i / GI_KC, k = i % GI_KC;
            w_l[k][r] = w_ih[(n0 + r) * D_IN + k0 + k];
        }
        __syncthreads();
        #pragma unroll 2
        for (int k = 0; k < GI_KC; ++k) {
            const float x0 = x_l[k][tq4 + 0], x1 = x_l[k][tq4 + 1];
            const float x2 = x_l[k][tq4 + 2], x3 = x_l[k][tq4 + 3];
            const float v0 = w_l[k][jq4 + 0], v1 = w_l[k][jq4 + 1];
            const float v2 = w_l[k][jq4 + 2], v3 = w_l[k][jq4 + 3];
            acc[0][0] = fmaf(x0, v0, acc[0][0]); acc[0][1] = fmaf(x0, v1, acc[0][1]);
            acc[0][2] = fmaf(x0, v2, acc[0][2]); acc[0][3] = fmaf(x0, v3, acc[0][3]);
            acc[1][0] = fmaf(x1, v0, acc[1][0]); acc[1][1] = fmaf(x1, v1, acc[1][1]);
            acc[1][2] = fmaf(x1, v2, acc[1][2]); acc[1][3] = fmaf(x1, v3, acc[1][3]);
            acc[2][0] = fmaf(x2, v0, acc[2][0]); acc[2][1] = fmaf(x2, v1, acc[2][1]);
            acc[2][2] = fmaf(x2, v2, acc[2][2]); acc[2][3] = fmaf(x2, v3, acc[2][3]);
            acc[3][0] = fmaf(x3, v0, acc[3][0]); acc[3][1] = fmaf(x3, v1, acc[3][1]);
            acc[3][2] = fmaf(x3, v2, acc[3][2]); acc[3][3] = fmaf(x3, v3, acc[3][3]);
        }
        __syncthreads();
    }
    const float b0 = b_ih[n0 + jq4 + 0], b1 = b_ih[n0 + jq4 + 1];
    const float b2 = b_ih[n0 + jq4 + 2], b3 = b_ih[n0 + jq4 + 3];
    #pragma unroll
    for (int i = 0; i < 4; ++i) {
        const int row = m0 + tq4 + i;
        const int q = row / T_MAX, t = row - q * T_MAX;
        float4 v = make_float4(acc[i][0] + b0, acc[i][1] + b1, acc[i][2] + b2, acc[i][3] + b3);
        *(float4*)&gi[(q * T_MAX + t) * 768 + n0 + jq4] = v;
    }
}

// ---------------------------------------------------------------- cooperative GRU + lang fold (R16)
__global__ __launch_bounds__(384, 1) void k_gru8(const float* __restrict__ gi,
                                                 const float* __restrict__ w_hh,
                                                 const float* __restrict__ b_hh,
                                                 const int* __restrict__ lang_len,
                                                 float* __restrict__ hg,
                                                 float* __restrict__ hbuf,
                                                 const float* __restrict__ w1t,
                                                 const float* __restrict__ b1,
                                                 const float* __restrict__ w2t,
                                                 const float* __restrict__ b2,
                                                 const float* __restrict__ fwt,
                                                 const float* __restrict__ fuse_b,
                                                 float* __restrict__ langc,
                                                 int* __restrict__ qdone) {
    __shared__ __align__(16) float wlds[96 * 256];
    __shared__ __align__(16) float hlq[4 * 68];
    __shared__ float ghl[96];
    __shared__ float gil[T_MAX * 96];

    const int tid = threadIdx.x;
    const int q = blockIdx.x >> 3, b = blockIdx.x & 7;
    int len = lang_len[q]; if (len > T_MAX) len = T_MAX; if (len < 1) len = 1;

    {
        const float4* src4 = (const float4*)w_hh;
        float4* dst4 = (float4*)wlds;
        for (int i = tid; i < 96 * 64; i += 384) {
            const int r = i >> 6, c = i & 63;
            const int grow = ((r >> 5) << 8) + (b << 5) + (r & 31);
            dst4[r * 64 + (c ^ (r & 7))] = src4[grow * 64 + c];
        }
    }
    for (int i = tid; i < len * 96; i += 384) {
        const int t = i / 96, r = i % 96;
        gil[i] = gi[(q * T_MAX + t) * 768 + ((r >> 5) << 8) + (b << 5) + (r & 31)];
    }
    __syncthreads();

    float hfin = 0.f;
    {
        float hnew = 0.f;
        if (tid < 32) {
            const float bhr = b_hh[(b << 5) + tid];
            const float bhz = b_hh[H_DIM + (b << 5) + tid];
            const float bhn = b_hh[2 * H_DIM + (b << 5) + tid];
            const float r = sigmoidf_(gil[tid] + bhr);
            const float z = sigmoidf_(gil[32 + tid] + bhz);
            const float n = tanhf(gil[64 + tid] + r * bhn);
            hnew = (1.f - z) * n;
            if (len == 1) hfin = hnew;
        }
        if (tid < 64 && len > 1) {
            const float a0 = __shfl(hnew, 2 * (tid & 15));
            const float a1 = __shfl(hnew, 2 * (tid & 15) + 1);
            if (tid < 16) {
                unsigned long long* dst = (unsigned long long*)(hg + q * H_DIM + (b << 5));
                __hip_atomic_store(dst + tid, pack2(a0, a1), __ATOMIC_RELAXED, __HIP_MEMORY_SCOPE_AGENT);
            }
        }
    }

    const int row = tid >> 2, ql = tid & 3;
    const float bh = b_hh[((row >> 5) << 8) + (b << 5) + (row & 31)];
    const int rx = row & 7;
    const float4* wrow4 = (const float4*)wlds + row * 64;
    const int cbase = ql << 4;

    for (int t = 1; t < len; ++t) {
        if (tid < 128) {
            const unsigned long long* src =
                (const unsigned long long*)(hg + (size_t)(t - 1) * (Q_TOT * H_DIM) + q * H_DIM);
            unsigned long long v;
            while ((v = __hip_atomic_load(src + tid, __ATOMIC_RELAXED,
                                          __HIP_MEMORY_SCOPE_AGENT)) == SENT64)
                __builtin_amdgcn_s_sleep(1);
            const int k = 2 * tid;
            const int o = (k >> 6) * 68 + (k & 63);
            hlq[o]     = __uint_as_float((unsigned)(v & 0xffffffffu));
            hlq[o + 1] = __uint_as_float((unsigned)(v >> 32));
        }
        __syncthreads();
        float hold = 0.f;
        if (tid < 32) { const int k = (b << 5) + tid; hold = hlq[(k >> 6) * 68 + (k & 63)]; }
        const float4* h4 = (const float4*)(hlq + ql * 68);
        float ax = 0.f, ay = 0.f, az = 0.f, aw = 0.f;
        #pragma unroll
        for (int i = 0; i < 16; ++i) {
            const float4 wv = wrow4[(cbase + i) ^ rx];
            const float4 hv = h4[i];
            ax = fmaf(wv.x, hv.x, ax);
            ay = fmaf(wv.y, hv.y, ay);
            az = fmaf(wv.z, hv.z, az);
            aw = fmaf(wv.w, hv.w, aw);
        }
        float s = (ax + ay) + (az + aw);
        s += __shfl_xor(s, 1);
        s += __shfl_xor(s, 2);
        if (ql == 0) ghl[row] = s + bh;
        __syncthreads();
        float hnew = 0.f;
        if (tid < 32) {
            const float* gt_ = gil + t * 96;
            const float r = sigmoidf_(gt_[tid] + ghl[tid]);
            const float z = sigmoidf_(gt_[32 + tid] + ghl[32 + tid]);
            const float n = tanhf(gt_[64 + tid] + r * ghl[64 + tid]);
            hnew = (1.f - z) * n + z * hold;
            if (t == len - 1) hfin = hnew;
        }
        if (tid < 64 && t < len - 1) {
            const float a0 = __shfl(hnew, 2 * (tid & 15));
            const float a1 = __shfl(hnew, 2 * (tid & 15) + 1);
            if (tid < 16) {
                unsigned long long* dst =
                    (unsigned long long*)(hg + (size_t)t * (Q_TOT * H_DIM) + q * H_DIM + (b << 5));
                __hip_atomic_store(dst + tid, pack2(a0, a1), __ATOMIC_RELAXED, __HIP_MEMORY_SCOPE_AGENT);
            }
        }
    }

    if (tid < 32)
        __hip_atomic_store(&hbuf[q * H_DIM + (b << 5) + tid], hfin,
                           __ATOMIC_RELAXED, __HIP_MEMORY_SCOPE_AGENT);
    asm volatile("s_waitcnt vmcnt(0)" ::: "memory");
    __syncthreads();
    if (tid == 0)
        __hip_atomic_fetch_add(&qdone[q], 1, __ATOMIC_RELAXED, __HIP_MEMORY_SCOPE_AGENT);
    if (b != 0) return;

    if (tid == 0) {
        while (__hip_atomic_load(&qdone[q], __ATOMIC_RELAXED, __HIP_MEMORY_SCOPE_AGENT) < 8)
            __builtin_amdgcn_s_sleep(2);
    }
    __syncthreads();
    float* hql = gil;
    float* t1l = gil + 256;
    float* lgl = gil + 320;
    if (tid < H_DIM)
        hql[tid] = __hip_atomic_load(&hbuf[q * H_DIM + tid], __ATOMIC_RELAXED, __HIP_MEMORY_SCOPE_AGENT);
    __syncthreads();
    if (tid < 256) {
        const int c = tid >> 2, qq = tid & 3;
        float a = 0.f;
        #pragma unroll 8
        for (int j = 0; j < 64; ++j) {
            const int k = (qq << 6) + j;
            a = fmaf(w1t[k * D_LANG + c], hql[k], a);
        }
        a += __shfl_xor(a, 1);
        a += __shfl_xor(a, 2);
        if (qq == 0) t1l[c] = fmaxf(a + b1[c], 0.f);
    }
    __syncthreads();
    if (tid < 256) {
        const int c = tid >> 2, qq = tid & 3;
        float a = 0.f;
        #pragma unroll
        for (int j = 0; j < 16; ++j) {
            const int k = (qq << 4) + j;
            a = fmaf(w2t[k * D_LANG + c], t1l[k], a);
        }
        a += __shfl_xor(a, 1);
        a += __shfl_xor(a, 2);
        if (qq == 0) lgl[c] = a + b2[c];
    }
    __syncthreads();
    if (tid < 256) {
        const int d = tid >> 1, hh = tid & 1;
        float a = 0.f;
        #pragma unroll 8
        for (int j = 0; j < 32; ++j) {
            const int k = (hh << 5) + j;
            a = fmaf(fwt[(D_CAT + k) * D_FUSE + d], lgl[k], a);
        }
        a += __shfl_xor(a, 1);
        if (hh == 0) langc[q * D_FUSE + d] = a + fuse_b[d];
    }
}

// ---------------------------------------------------------------- k_tail v3: 1024 blocks (all co-resident)
// blocks <625: phase F (1 tile each); blocks 0..511: phase A; ALL: wait best flags, phase O.
__global__ __launch_bounds__(256, 3) void k_tail(const float* __restrict__ feat,
                                                 const float* __restrict__ coords,
                                                 const int* __restrict__ grps,
                                                 const float* __restrict__ langc,
                                                 const float* __restrict__ fwt,
                                                 const float* __restrict__ wdr_g,
                                                 const float* __restrict__ heat_b,
                                                 float* __restrict__ grp_part,
                                                 int* __restrict__ cnt_part,
                                                 float* __restrict__ grp2,
                                                 int* __restrict__ cnt2,
                                                 int* __restrict__ best,
                                                 const int* __restrict__ supervox,
                                                 const int* __restrict__ gt,
                                                 float* __restrict__ out,
                                                 int* __restrict__ syncs) {
    int* interG = syncs;
    int* unionG = syncs + 32;
    int* t_out  = syncs + 64;
    int* gtick  = syncs + 65;
    int* qtick  = syncs + 98;
    const int tid = threadIdx.x;
    const int bid = blockIdx.x;

    __shared__ __align__(16) float svin[SCHUNK][68];
    __shared__ __align__(16) float svp[SCHUNK][132];
    __shared__ float score[SCHUNK][Q_TOT];
    __shared__ int grps_l[SCHUNK];
    __shared__ float ps[4][G_TOT];
    __shared__ int   pc[4][G_TOT];
    __shared__ float sc[G_TOT];
    __shared__ int bl[Q_TOT];
    __shared__ int gm[G_TOT];
    __shared__ int bi_s[Q_TOT], bu_s[Q_TOT];
    __shared__ int islast;

    // ================= phase F: per-tile fused score + group partials (blocks < 625)
    if (bid < NBLK3) {
        const int s0 = bid * SCHUNK;
        const int dsl = tid & 7, q = tid >> 3;
        float lc[16], wdr[16];
        #pragma unroll
        for (int i = 0; i < 16; ++i) {
            const int d = dsl * 16 + i;
            lc[i]  = langc[q * D_FUSE + d];
            wdr[i] = wdr_g[d];
        }
        const float hbd = heat_b[1] - heat_b[0];

        for (int i = tid; i < SCHUNK * D_SV; i += 256) {
            const int r = i >> 6, c = i & 63;
            svin[r][c] = feat[(s0 + r) * D_SV + c];
        }
        if (tid < SCHUNK * 3) { const int r = tid / 3, c = tid % 3; svin[r][D_SV + c] = coords[(s0 + r) * 3 + c]; }
        if (tid < SCHUNK) grps_l[tid] = grps[s0 + tid];
        __syncthreads();

        {
            const int d = tid & 127, sl0 = tid >> 7;
            float acc[16];
            #pragma unroll
            for (int i = 0; i < 16; ++i) acc[i] = 0.f;
            for (int k4 = 0; k4 < 16; ++k4) {
                const float w0 = fwt[(4 * k4 + 0) * D_FUSE + d];
                const float w1 = fwt[(4 * k4 + 1) * D_FUSE + d];
                const float w2 = fwt[(4 * k4 + 2) * D_FUSE + d];
                const float w3 = fwt[(4 * k4 + 3) * D_FUSE + d];
                #pragma unroll
                for (int i = 0; i < 16; ++i) {
                    const float4 xv = *(const float4*)&svin[sl0 + 2 * i][4 * k4];
                    acc[i] = fmaf(xv.x, w0, fmaf(xv.y, w1, fmaf(xv.z, w2, fmaf(xv.w, w3, acc[i]))));
                }
            }
            for (int k = 64; k < D_CAT; ++k) {
                const float wv = fwt[k * D_FUSE + d];
                #pragma unroll
                for (int i = 0; i < 16; ++i)
                    acc[i] = fmaf(svin[sl0 + 2 * i][k], wv, acc[i]);
            }
            #pragma unroll
            for (int i = 0; i < 16; ++i) svp[sl0 + 2 * i][d] = acc[i];
        }
        __syncthreads();

        for (int sl = 0; sl < SCHUNK; ++sl) {
            const float4* sv4 = (const float4*)(&svp[sl][dsl * 16]);
            float part = 0.f;
            #pragma unroll
            for (int j = 0; j < 4; ++j) {
                const float4 v = sv4[j];
                part = fmaf(fmaxf(v.x + lc[4*j+0], 0.f), wdr[4*j+0], part);
                part = fmaf(fmaxf(v.y + lc[4*j+1], 0.f), wdr[4*j+1], part);
                part = fmaf(fmaxf(v.z + lc[4*j+2], 0.f), wdr[4*j+2], part);
                part = fmaf(fmaxf(v.w + lc[4*j+3], 0.f), wdr[4*j+3], part);
            }
            part += __shfl_xor(part, 1);
            part += __shfl_xor(part, 2);
            part += __shfl_xor(part, 4);
            if (dsl == 0) score[sl][q] = sigmoidf_(part + hbd);
        }
        __syncthreads();

        for (int i = 0; i < 8; ++i) {
            const int cell = tid + 256 * i;
            const int qq = cell >> 6, g = cell & 63;
            float sum = 0.f;
            #pragma unroll
            for (int sl = 0; sl < SCHUNK; ++sl)
                sum += (grps_l[sl] == g) ? score[sl][qq] : 0.f;
            __hip_atomic_store(&grp_part[bid * (Q_TOT * G_TOT) + cell], sum,
                               __ATOMIC_RELAXED, __HIP_MEMORY_SCOPE_AGENT);
            if (cell < G_TOT) {
                int c = 0;
                #pragma unroll
                for (int sl = 0; sl < SCHUNK; ++sl) c += (grps_l[sl] == g);
                __hip_atomic_store(&cnt_part[bid * G_TOT + g], c,
                                   __ATOMIC_RELAXED, __HIP_MEMORY_SCOPE_AGENT);
            }
        }
        asm volatile("s_waitcnt vmcnt(0)" ::: "memory");
        __syncthreads();
        if (tid == 0)
            __hip_atomic_fetch_add(&syncs[160 + 32 * (bid / PTILES)], 1,
                                   __ATOMIC_RELAXED, __HIP_MEMORY_SCOPE_AGENT);
    }

    // ================= phase A: two-stage reduction + argmax (blocks 0..511)
    if (bid < Q_TOT * PCHUNK) {
        const int q = bid & 31, c = bid >> 5;
        const int b0 = c * PTILES;
        int b1 = b0 + PTILES; if (b1 > NBLK3) b1 = NBLK3;
        if (tid == 0) {
            int* tc = &syncs[160 + 32 * c];
            const int tgt = b1 - b0;
            while (__hip_atomic_load(tc, __ATOMIC_RELAXED, __HIP_MEMORY_SCOPE_AGENT) < tgt)
                __builtin_amdgcn_s_sleep(4);
        }
        __syncthreads();
        const int bq = tid >> 6, g = tid & 63;
        float acc = 0.f; int cacc = 0;
        for (int b = b0 + bq; b < b1; b += 4) {
            acc  += grp_part[b * (Q_TOT * G_TOT) + q * G_TOT + g];
            cacc += cnt_part[b * G_TOT + g];
        }
        ps[bq][g] = acc; pc[bq][g] = cacc;
        __syncthreads();
        if (tid < G_TOT) {
            const float s = ((ps[0][tid] + ps[1][tid]) + ps[2][tid]) + ps[3][tid];
            const int  cc = ((pc[0][tid] + pc[1][tid]) + pc[2][tid]) + pc[3][tid];
            __hip_atomic_store(&grp2[(c * Q_TOT + q) * G_TOT + tid], s,
                               __ATOMIC_RELAXED, __HIP_MEMORY_SCOPE_AGENT);
            __hip_atomic_store(&cnt2[(c * Q_TOT + q) * G_TOT + tid], cc,
                               __ATOMIC_RELAXED, __HIP_MEMORY_SCOPE_AGENT);
        }
        __shared__ int myturn;
        asm volatile("s_waitcnt vmcnt(0)" ::: "memory");
        if (tid == 0) {
            const int old = __hip_atomic_fetch_add(&qtick[q], 1, __ATOMIC_RELAXED, __HIP_MEMORY_SCOPE_AGENT);
            myturn = (old == PCHUNK - 1) ? 1 : 0;
        }
        __syncthreads();
        if (myturn) {
            if (tid < G_TOT) {
                float s = 0.f; int cc = 0;
                #pragma unroll
                for (int c2 = 0; c2 < PCHUNK; ++c2) {
                    s  += grp2[(c2 * Q_TOT + q) * G_TOT + tid];
                    cc += cnt2[(c2 * Q_TOT + q) * G_TOT + tid];
                }
                sc[tid] = s / (float)cc;
            }
            __syncthreads();
            if (tid == 0) {
                float bv = sc[0]; int bi = 0;
                for (int g2 = 1; g2 < G_TOT; ++g2) if (sc[g2] > bv) { bv = sc[g2]; bi = g2; }
                __hip_atomic_store(&best[q], bi, __ATOMIC_RELAXED, __HIP_MEMORY_SCOPE_AGENT);
                asm volatile("s_waitcnt vmcnt(0)" ::: "memory");
                const int old = __hip_atomic_fetch_add(gtick, 1, __ATOMIC_RELAXED, __HIP_MEMORY_SCOPE_AGENT);
                if (old == Q_TOT - 1) {
                    #pragma unroll
                    for (int f = 0; f < 8; ++f)
                        __hip_atomic_store(&syncs[672 + 32 * f], 1,
                                           __ATOMIC_RELAXED, __HIP_MEMORY_SCOPE_AGENT);
                }
            }
        }
    }

    // ================= wait best-ready (spread flags, long backoff)
    if (tid == 0) {
        int* fl = &syncs[672 + 32 * (bid & 7)];
        while (__hip_atomic_load(fl, __ATOMIC_RELAXED, __HIP_MEMORY_SCOPE_AGENT) == 0)
            __builtin_amdgcn_s_sleep(16);
    }
    __syncthreads();

    if (tid < Q_TOT) bl[tid] = best[tid];
    __syncthreads();
    if (tid < G_TOT) {
        int m = 0;
        #pragma unroll
        for (int qq = 0; qq < Q_TOT; ++qq) m |= (bl[qq] == tid) ? (1 << qq) : 0;
        gm[tid] = m;
    }
    __syncthreads();

    // ================= phase O: obj_pts + inter/union + iou (1024 blocks)
    {
        const int gidx = bid * 256 + tid;
        const int q4 = (gidx & 7) * 4;
        const int nstride = (TAIL_GRID * 256) >> 3;    // 32768
        int a0 = 0, a1 = 0, a2 = 0, a3 = 0;
        int u0 = 0, u1 = 0, u2 = 0, u3 = 0;
        for (int n = gidx >> 3; n < N_TOT; n += nstride) {
            const int m = gm[grps[supervox[n]]];
            const int4 g4 = *(const int4*)&gt[n * Q_TOT + q4];
            const int o0 = (m >> (q4 + 0)) & 1;
            const int o1 = (m >> (q4 + 1)) & 1;
            const int o2 = (m >> (q4 + 2)) & 1;
            const int o3 = (m >> (q4 + 3)) & 1;
            *(float4*)&out[n * Q_TOT + q4] =
                make_float4((float)o0, (float)o1, (float)o2, (float)o3);
            a0 += o0 & g4.x; u0 += o0 | g4.x;
            a1 += o1 & g4.y; u1 += o1 | g4.y;
            a2 += o2 & g4.z; u2 += o2 | g4.z;
            a3 += o3 & g4.w; u3 += o3 | g4.w;
        }
        if (tid < Q_TOT) { bi_s[tid] = 0; bu_s[tid] = 0; }
        __syncthreads();
        atomicAdd(&bi_s[q4 + 0], a0); atomicAdd(&bu_s[q4 + 0], u0);
        atomicAdd(&bi_s[q4 + 1], a1); atomicAdd(&bu_s[q4 + 1], u1);
        atomicAdd(&bi_s[q4 + 2], a2); atomicAdd(&bu_s[q4 + 2], u2);
        atomicAdd(&bi_s[q4 + 3], a3); atomicAdd(&bu_s[q4 + 3], u3);
        __syncthreads();
        if (tid < Q_TOT) { atomicAdd(&interG[tid], bi_s[tid]); atomicAdd(&unionG[tid], bu_s[tid]); }
        asm volatile("s_waitcnt vmcnt(0)" ::: "memory");
        if (tid == 0) {
            const int old = __hip_atomic_fetch_add(t_out, 1, __ATOMIC_RELAXED, __HIP_MEMORY_SCOPE_AGENT);
            islast = (old == TAIL_GRID - 1) ? 1 : 0;
        }
        __syncthreads();
        if (islast && tid < Q_TOT) {
            const int iv = __hip_atomic_load(&interG[tid], __ATOMIC_RELAXED, __HIP_MEMORY_SCOPE_AGENT);
            const int uv = __hip_atomic_load(&unionG[tid], __ATOMIC_RELAXED, __HIP_MEMORY_SCOPE_AGENT);
            out[(size_t)N_TOT * Q_TOT + tid] = (float)iv / ((float)uv + 1e-5f);
        }
    }
}

extern "C" void kernel_launch(void* const* d_in, const int* in_sizes, int n_in,
                              void* d_out, int out_size, void* d_ws, size_t ws_size,
                              hipStream_t stream) {
    const float* lang_feat = (const float*)d_in[0];
    const float* feat      = (const float*)d_in[1];
    const float* coords    = (const float*)d_in[2];
    const int*   lang_len  = (const int*)d_in[3];
    const int*   grps      = (const int*)d_in[4];
    const int*   supervox  = (const int*)d_in[5];
    const int*   gt        = (const int*)d_in[6];
    const float* w_ih      = (const float*)d_in[7];
    const float* w_hh      = (const float*)d_in[8];
    const float* b_ih      = (const float*)d_in[9];
    const float* b_hh      = (const float*)d_in[10];
    const float* sqz_w1    = (const float*)d_in[11];
    const float* sqz_b1    = (const float*)d_in[12];
    const float* sqz_w2    = (const float*)d_in[13];
    const float* sqz_b2    = (const float*)d_in[14];
    const float* fuse_w    = (const float*)d_in[15];
    const float* fuse_b    = (const float*)d_in[16];
    const float* heat_w    = (const float*)d_in[17];
    const float* heat_b    = (const float*)d_in[18];
    float* out = (float*)d_out;

    float* gi       = (float*)d_ws;                       // 737280
    float* hbuf     = gi + 737280;                        // 8192
    float* langc    = hbuf + 8192;                        // 4096
    float* grp_part = langc + 4096;                       // 1280000
    int*   cnt_part = (int*)(grp_part + NBLK3 * 2048);    // 40000
    int*   best     = cnt_part + NBLK3 * 64;              // 32
    int*   syncs    = best + 32;                          // SYNCS_N
    float* hg       = (float*)(syncs + SYNCS_N);          // 245760
    float* fwt      = hg + HG_ELEMS;                      // 16768
    float* w1t      = fwt + FW_LD * D_FUSE;               // 16384
    float* w2t      = w1t + H_DIM * D_LANG;               // 4096
    float* wdr      = w2t + D_LANG * D_LANG;              // 128
    float* grp2     = wdr + 128;                          // 32768
    int*   cnt2     = (int*)(grp2 + PCHUNK * Q_TOT * G_TOT); // 32768

    k_gi   <<<GI_GRID + 9, 128, 0, stream>>>(lang_feat, w_ih, b_ih, fuse_w, sqz_w1, sqz_w2, heat_w,
                                             gi, fwt, w1t, w2t, wdr, hg, syncs);
    k_gru8 <<<Q_TOT * 8, 384, 0, stream>>>(gi, w_hh, b_hh, lang_len, hg, hbuf,
                                           w1t, sqz_b1, w2t, sqz_b2, fwt, fuse_b, langc,
                                           syncs + 66);
    k_tail <<<TAIL_GRID, 256, 0, stream>>>(feat, coords, grps, langc, fwt, wdr, heat_b,
                                           grp_part, cnt_part, grp2, cnt2, best,
                                           supervox, gt, out, syncs);
}

// Round 19
// 203.591 us; speedup vs baseline: 1.3638x; 1.0148x over previous
//
#include <hip/hip_runtime.h>
#include <hip/hip_bf16.h>
#include <math.h>

#define S_TOT 20000
#define Q_TOT 32
#define N_TOT 200000
#define T_MAX 30
#define G_TOT 64
#define D_IN 300
#define H_DIM 256
#define D_SV 64
#define D_LANG 64
#define D_FUSE 128
#define D_CAT 67
#define FW_LD 131
#define SCHUNK 32
#define NBLK3 (S_TOT / SCHUNK)   // 625
#define SENT64 0xFFFFFFFFFFFFFFFFull
#define PCHUNK 16
#define PTILES 40
#define TAIL_GRID 1024

// k_gi GEMM tiling
#define GI_MT 32
#define GI_NT 64
#define GI_KC 100
#define GI_NB 12
#define GI_GRID (30 * GI_NB)     // 360
#define HG_ELEMS (30 * Q_TOT * H_DIM)

// syncs ints, ALL hot counters line-spaced (32 ints = 128 B apart):
// interG[q]=32q | unionG[q]=1024+32q | qdone[q]=2048+32q | qtick[q]=3072+32q
// tfc[c]=4096+32c (c<16) | bflag[i]=4608+32i (i<8) | t_sub[i]=4864+32i (i<8) | t_top=5152
#define SYNCS_N 5376

__device__ __forceinline__ float sigmoidf_(float x) { return 1.0f / (1.0f + expf(-x)); }
__device__ __forceinline__ unsigned long long pack2(float a, float b) {
    return ((unsigned long long)__float_as_uint(b) << 32) | (unsigned long long)__float_as_uint(a);
}

// ---------------------------------------------------------------- k_gi
__global__ __launch_bounds__(128) void k_gi(const float* __restrict__ lang_feat,
                                            const float* __restrict__ w_ih,
                                            const float* __restrict__ b_ih,
                                            const float* __restrict__ fuse_w,
                                            const float* __restrict__ sqz_w1,
                                            const float* __restrict__ sqz_w2,
                                            const float* __restrict__ heat_w,
                                            float* __restrict__ gi,
                                            float* __restrict__ fwt,
                                            float* __restrict__ w1t,
                                            float* __restrict__ w2t,
                                            float* __restrict__ wdr,
                                            float* __restrict__ hg,
                                            int* __restrict__ syncs) {
    const int tid = threadIdx.x;
    if (blockIdx.x >= GI_GRID) {
        const int xb = blockIdx.x - GI_GRID;
        if (xb == 0) {
            for (int i = tid; i < FW_LD * D_FUSE; i += 128)
                fwt[(i % FW_LD) * D_FUSE + (i / FW_LD)] = fuse_w[i];
            for (int i = tid; i < D_LANG * H_DIM; i += 128)
                w1t[(i & 255) * D_LANG + (i >> 8)] = sqz_w1[i];
            for (int i = tid; i < D_LANG * D_LANG; i += 128)
                w2t[(i & 63) * D_LANG + (i >> 6)] = sqz_w2[i];
            if (tid < D_FUSE) wdr[tid] = heat_w[D_FUSE + tid] - heat_w[tid];
        } else {
            const int fb = xb - 1;                        // 0..7
            const int per4 = HG_ELEMS / 4 / 8;
            float4* dst = (float4*)hg + fb * per4;
            const float4 sv = make_float4(__uint_as_float(0xFFFFFFFFu), __uint_as_float(0xFFFFFFFFu),
                                          __uint_as_float(0xFFFFFFFFu), __uint_as_float(0xFFFFFFFFu));
            for (int i = tid; i < per4; i += 128) dst[i] = sv;
            if (fb == 0) for (int i = tid; i < SYNCS_N; i += 128) syncs[i] = 0;
        }
        return;
    }
    __shared__ float x_l[GI_KC][GI_MT + 1];
    __shared__ float w_l[GI_KC][GI_NT + 1];
    const int mb = blockIdx.x / GI_NB, nb = blockIdx.x % GI_NB;
    const int m0 = mb * GI_MT, n0 = nb * GI_NT;
    const int tq4 = (tid >> 4) * 4, jq4 = (tid & 15) * 4;

    float acc[4][4];
    #pragma unroll
    for (int i = 0; i < 4; ++i)
        #pragma unroll
        for (int j = 0; j < 4; ++j) acc[i][j] = 0.f;

    for (int kc = 0; kc < 3; ++kc) {
        const int k0 = kc * GI_KC;
        for (int i = tid; i < GI_MT * GI_KC; i += 128) {
            const int r = i / GI_KC, k = i % GI_KC;
            const int row = m0 + r, q = row / T_MAX, t = row - q * T_MAX;
            x_l[k][r] = lang_feat[(q * T_MAX + t) * D_IN + k0 + k];
        }
        for (int i = tid; i < GI_NT * GI_KC; i += 128) {
            const int r = i / GI_KC, k = i % GI_KC;
            w_l[k][r] = w_ih[(n0 + r) * D_IN + k0 + k];
        }
        __syncthreads();
        #pragma unroll 2
        for (int k = 0; k < GI_KC; ++k) {
            const float x0 = x_l[k][tq4 + 0], x1 = x_l[k][tq4 + 1];
            const float x2 = x_l[k][tq4 + 2], x3 = x_l[k][tq4 + 3];
            const float v0 = w_l[k][jq4 + 0], v1 = w_l[k][jq4 + 1];
            const float v2 = w_l[k][jq4 + 2], v3 = w_l[k][jq4 + 3];
            acc[0][0] = fmaf(x0, v0, acc[0][0]); acc[0][1] = fmaf(x0, v1, acc[0][1]);
            acc[0][2] = fmaf(x0, v2, acc[0][2]); acc[0][3] = fmaf(x0, v3, acc[0][3]);
            acc[1][0] = fmaf(x1, v0, acc[1][0]); acc[1][1] = fmaf(x1, v1, acc[1][1]);
            acc[1][2] = fmaf(x1, v2, acc[1][2]); acc[1][3] = fmaf(x1, v3, acc[1][3]);
            acc[2][0] = fmaf(x2, v0, acc[2][0]); acc[2][1] = fmaf(x2, v1, acc[2][1]);
            acc[2][2] = fmaf(x2, v2, acc[2][2]); acc[2][3] = fmaf(x2, v3, acc[2][3]);
            acc[3][0] = fmaf(x3, v0, acc[3][0]); acc[3][1] = fmaf(x3, v1, acc[3][1]);
            acc[3][2] = fmaf(x3, v2, acc[3][2]); acc[3][3] = fmaf(x3, v3, acc[3][3]);
        }
        __syncthreads();
    }
    const float b0 = b_ih[n0 + jq4 + 0], b1 = b_ih[n0 + jq4 + 1];
    const float b2 = b_ih[n0 + jq4 + 2], b3 = b_ih[n0 + jq4 + 3];
    #pragma unroll
    for (int i = 0; i < 4; ++i) {
        const int row = m0 + tq4 + i;
        const int q = row / T_MAX, t = row - q * T_MAX;
        float4 v = make_float4(acc[i][0] + b0, acc[i][1] + b1, acc[i][2] + b2, acc[i][3] + b3);
        *(float4*)&gi[(q * T_MAX + t) * 768 + n0 + jq4] = v;
    }
}

// ---------------------------------------------------------------- cooperative GRU + lang fold
__global__ __launch_bounds__(384, 1) void k_gru8(const float* __restrict__ gi,
                                                 const float* __restrict__ w_hh,
                                                 const float* __restrict__ b_hh,
                                                 const int* __restrict__ lang_len,
                                                 float* __restrict__ hg,
                                                 float* __restrict__ hbuf,
                                                 const float* __restrict__ w1t,
                                                 const float* __restrict__ b1,
                                                 const float* __restrict__ w2t,
                                                 const float* __restrict__ b2,
                                                 const float* __restrict__ fwt,
                                                 const float* __restrict__ fuse_b,
                                                 float* __restrict__ langc,
                                                 int* __restrict__ qdone) {   // line-spaced: qdone[32*q]
    __shared__ __align__(16) float wlds[96 * 256];
    __shared__ __align__(16) float hlq[4 * 68];
    __shared__ float ghl[96];
    __shared__ float gil[T_MAX * 96];

    const int tid = threadIdx.x;
    const int q = blockIdx.x >> 3, b = blockIdx.x & 7;
    int len = lang_len[q]; if (len > T_MAX) len = T_MAX; if (len < 1) len = 1;

    {
        const float4* src4 = (const float4*)w_hh;
        float4* dst4 = (float4*)wlds;
        for (int i = tid; i < 96 * 64; i += 384) {
            const int r = i >> 6, c = i & 63;
            const int grow = ((r >> 5) << 8) + (b << 5) + (r & 31);
            dst4[r * 64 + (c ^ (r & 7))] = src4[grow * 64 + c];
        }
    }
    for (int i = tid; i < len * 96; i += 384) {
        const int t = i / 96, r = i % 96;
        gil[i] = gi[(q * T_MAX + t) * 768 + ((r >> 5) << 8) + (b << 5) + (r & 31)];
    }
    __syncthreads();

    float hfin = 0.f;
    {
        float hnew = 0.f;
        if (tid < 32) {
            const float bhr = b_hh[(b << 5) + tid];
            const float bhz = b_hh[H_DIM + (b << 5) + tid];
            const float bhn = b_hh[2 * H_DIM + (b << 5) + tid];
            const float r = sigmoidf_(gil[tid] + bhr);
            const float z = sigmoidf_(gil[32 + tid] + bhz);
            const float n = tanhf(gil[64 + tid] + r * bhn);
            hnew = (1.f - z) * n;
            if (len == 1) hfin = hnew;
        }
        if (tid < 64 && len > 1) {
            const float a0 = __shfl(hnew, 2 * (tid & 15));
            const float a1 = __shfl(hnew, 2 * (tid & 15) + 1);
            if (tid < 16) {
                unsigned long long* dst = (unsigned long long*)(hg + q * H_DIM + (b << 5));
                __hip_atomic_store(dst + tid, pack2(a0, a1), __ATOMIC_RELAXED, __HIP_MEMORY_SCOPE_AGENT);
            }
        }
    }

    const int row = tid >> 2, ql = tid & 3;
    const float bh = b_hh[((row >> 5) << 8) + (b << 5) + (row & 31)];
    const int rx = row & 7;
    const float4* wrow4 = (const float4*)wlds + row * 64;
    const int cbase = ql << 4;

    for (int t = 1; t < len; ++t) {
        if (tid < 128) {
            const unsigned long long* src =
                (const unsigned long long*)(hg + (size_t)(t - 1) * (Q_TOT * H_DIM) + q * H_DIM);
            unsigned long long v;
            while ((v = __hip_atomic_load(src + tid, __ATOMIC_RELAXED,
                                          __HIP_MEMORY_SCOPE_AGENT)) == SENT64)
                __builtin_amdgcn_s_sleep(1);
            const int k = 2 * tid;
            const int o = (k >> 6) * 68 + (k & 63);
            hlq[o]     = __uint_as_float((unsigned)(v & 0xffffffffu));
            hlq[o + 1] = __uint_as_float((unsigned)(v >> 32));
        }
        __syncthreads();
        float hold = 0.f;
        if (tid < 32) { const int k = (b << 5) + tid; hold = hlq[(k >> 6) * 68 + (k & 63)]; }
        const float4* h4 = (const float4*)(hlq + ql * 68);
        float ax = 0.f, ay = 0.f, az = 0.f, aw = 0.f;
        #pragma unroll
        for (int i = 0; i < 16; ++i) {
            const float4 wv = wrow4[(cbase + i) ^ rx];
            const float4 hv = h4[i];
            ax = fmaf(wv.x, hv.x, ax);
            ay = fmaf(wv.y, hv.y, ay);
            az = fmaf(wv.z, hv.z, az);
            aw = fmaf(wv.w, hv.w, aw);
        }
        float s = (ax + ay) + (az + aw);
        s += __shfl_xor(s, 1);
        s += __shfl_xor(s, 2);
        if (ql == 0) ghl[row] = s + bh;
        __syncthreads();
        float hnew = 0.f;
        if (tid < 32) {
            const float* gt_ = gil + t * 96;
            const float r = sigmoidf_(gt_[tid] + ghl[tid]);
            const float z = sigmoidf_(gt_[32 + tid] + ghl[32 + tid]);
            const float n = tanhf(gt_[64 + tid] + r * ghl[64 + tid]);
            hnew = (1.f - z) * n + z * hold;
            if (t == len - 1) hfin = hnew;
        }
        if (tid < 64 && t < len - 1) {
            const float a0 = __shfl(hnew, 2 * (tid & 15));
            const float a1 = __shfl(hnew, 2 * (tid & 15) + 1);
            if (tid < 16) {
                unsigned long long* dst =
                    (unsigned long long*)(hg + (size_t)t * (Q_TOT * H_DIM) + q * H_DIM + (b << 5));
                __hip_atomic_store(dst + tid, pack2(a0, a1), __ATOMIC_RELAXED, __HIP_MEMORY_SCOPE_AGENT);
            }
        }
    }

    if (tid < 32)
        __hip_atomic_store(&hbuf[q * H_DIM + (b << 5) + tid], hfin,
                           __ATOMIC_RELAXED, __HIP_MEMORY_SCOPE_AGENT);
    asm volatile("s_waitcnt vmcnt(0)" ::: "memory");
    __syncthreads();
    if (tid == 0)
        __hip_atomic_fetch_add(&qdone[32 * q], 1, __ATOMIC_RELAXED, __HIP_MEMORY_SCOPE_AGENT);
    if (b != 0) return;

    if (tid == 0) {
        while (__hip_atomic_load(&qdone[32 * q], __ATOMIC_RELAXED, __HIP_MEMORY_SCOPE_AGENT) < 8)
            __builtin_amdgcn_s_sleep(2);
    }
    __syncthreads();
    float* hql = gil;
    float* t1l = gil + 256;
    float* lgl = gil + 320;
    if (tid < H_DIM)
        hql[tid] = __hip_atomic_load(&hbuf[q * H_DIM + tid], __ATOMIC_RELAXED, __HIP_MEMORY_SCOPE_AGENT);
    __syncthreads();
    if (tid < 256) {
        const int c = tid >> 2, qq = tid & 3;
        float a = 0.f;
        #pragma unroll 8
        for (int j = 0; j < 64; ++j) {
            const int k = (qq << 6) + j;
            a = fmaf(w1t[k * D_LANG + c], hql[k], a);
        }
        a += __shfl_xor(a, 1);
        a += __shfl_xor(a, 2);
        if (qq == 0) t1l[c] = fmaxf(a + b1[c], 0.f);
    }
    __syncthreads();
    if (tid < 256) {
        const int c = tid >> 2, qq = tid & 3;
        float a = 0.f;
        #pragma unroll
        for (int j = 0; j < 16; ++j) {
            const int k = (qq << 4) + j;
            a = fmaf(w2t[k * D_LANG + c], t1l[k], a);
        }
        a += __shfl_xor(a, 1);
        a += __shfl_xor(a, 2);
        if (qq == 0) lgl[c] = a + b2[c];
    }
    __syncthreads();
    if (tid < 256) {
        const int d = tid >> 1, hh = tid & 1;
        float a = 0.f;
        #pragma unroll 8
        for (int j = 0; j < 32; ++j) {
            const int k = (hh << 5) + j;
            a = fmaf(fwt[(D_CAT + k) * D_FUSE + d], lgl[k], a);
        }
        a += __shfl_xor(a, 1);
        if (hh == 0) langc[q * D_FUSE + d] = a + fuse_b[d];
    }
}

// ---------------------------------------------------------------- k_tail v4: line-spaced atomics everywhere
__global__ __launch_bounds__(256, 3) void k_tail(const float* __restrict__ feat,
                                                 const float* __restrict__ coords,
                                                 const int* __restrict__ grps,
                                                 const float* __restrict__ langc,
                                                 const float* __restrict__ fwt,
                                                 const float* __restrict__ wdr_g,
                                                 const float* __restrict__ heat_b,
                                                 float* __restrict__ grp_part,
                                                 int* __restrict__ cnt_part,
                                                 float* __restrict__ grp2,
                                                 int* __restrict__ cnt2,
                                                 int* __restrict__ best,
                                                 const int* __restrict__ supervox,
                                                 const int* __restrict__ gt,
                                                 float* __restrict__ out,
                                                 int* __restrict__ syncs) {
    const int tid = threadIdx.x;
    const int bid = blockIdx.x;

    __shared__ __align__(16) float svin[SCHUNK][68];
    __shared__ __align__(16) float svp[SCHUNK][132];
    __shared__ float score[SCHUNK][Q_TOT];
    __shared__ int grps_l[SCHUNK];
    __shared__ float ps[4][G_TOT];
    __shared__ int   pc[4][G_TOT];
    __shared__ float sc[G_TOT];
    __shared__ int bl[Q_TOT];
    __shared__ int gm[G_TOT];
    __shared__ int bi_s[Q_TOT], bu_s[Q_TOT];
    __shared__ int islast;

    // ================= phase F (blocks < 625)
    if (bid < NBLK3) {
        const int s0 = bid * SCHUNK;
        const int dsl = tid & 7, q = tid >> 3;
        float lc[16], wdr[16];
        #pragma unroll
        for (int i = 0; i < 16; ++i) {
            const int d = dsl * 16 + i;
            lc[i]  = langc[q * D_FUSE + d];
            wdr[i] = wdr_g[d];
        }
        const float hbd = heat_b[1] - heat_b[0];

        for (int i = tid; i < SCHUNK * D_SV; i += 256) {
            const int r = i >> 6, c = i & 63;
            svin[r][c] = feat[(s0 + r) * D_SV + c];
        }
        if (tid < SCHUNK * 3) { const int r = tid / 3, c = tid % 3; svin[r][D_SV + c] = coords[(s0 + r) * 3 + c]; }
        if (tid < SCHUNK) grps_l[tid] = grps[s0 + tid];
        __syncthreads();

        {
            const int d = tid & 127, sl0 = tid >> 7;
            float acc[16];
            #pragma unroll
            for (int i = 0; i < 16; ++i) acc[i] = 0.f;
            for (int k4 = 0; k4 < 16; ++k4) {
                const float w0 = fwt[(4 * k4 + 0) * D_FUSE + d];
                const float w1 = fwt[(4 * k4 + 1) * D_FUSE + d];
                const float w2 = fwt[(4 * k4 + 2) * D_FUSE + d];
                const float w3 = fwt[(4 * k4 + 3) * D_FUSE + d];
                #pragma unroll
                for (int i = 0; i < 16; ++i) {
                    const float4 xv = *(const float4*)&svin[sl0 + 2 * i][4 * k4];
                    acc[i] = fmaf(xv.x, w0, fmaf(xv.y, w1, fmaf(xv.z, w2, fmaf(xv.w, w3, acc[i]))));
                }
            }
            for (int k = 64; k < D_CAT; ++k) {
                const float wv = fwt[k * D_FUSE + d];
                #pragma unroll
                for (int i = 0; i < 16; ++i)
                    acc[i] = fmaf(svin[sl0 + 2 * i][k], wv, acc[i]);
            }
            #pragma unroll
            for (int i = 0; i < 16; ++i) svp[sl0 + 2 * i][d] = acc[i];
        }
        __syncthreads();

        for (int sl = 0; sl < SCHUNK; ++sl) {
            const float4* sv4 = (const float4*)(&svp[sl][dsl * 16]);
            float part = 0.f;
            #pragma unroll
            for (int j = 0; j < 4; ++j) {
                const float4 v = sv4[j];
                part = fmaf(fmaxf(v.x + lc[4*j+0], 0.f), wdr[4*j+0], part);
                part = fmaf(fmaxf(v.y + lc[4*j+1], 0.f), wdr[4*j+1], part);
                part = fmaf(fmaxf(v.z + lc[4*j+2], 0.f), wdr[4*j+2], part);
                part = fmaf(fmaxf(v.w + lc[4*j+3], 0.f), wdr[4*j+3], part);
            }
            part += __shfl_xor(part, 1);
            part += __shfl_xor(part, 2);
            part += __shfl_xor(part, 4);
            if (dsl == 0) score[sl][q] = sigmoidf_(part + hbd);
        }
        __syncthreads();

        for (int i = 0; i < 8; ++i) {
            const int cell = tid + 256 * i;
            const int qq = cell >> 6, g = cell & 63;
            float sum = 0.f;
            #pragma unroll
            for (int sl = 0; sl < SCHUNK; ++sl)
                sum += (grps_l[sl] == g) ? score[sl][qq] : 0.f;
            __hip_atomic_store(&grp_part[bid * (Q_TOT * G_TOT) + cell], sum,
                               __ATOMIC_RELAXED, __HIP_MEMORY_SCOPE_AGENT);
            if (cell < G_TOT) {
                int c = 0;
                #pragma unroll
                for (int sl = 0; sl < SCHUNK; ++sl) c += (grps_l[sl] == g);
                __hip_atomic_store(&cnt_part[bid * G_TOT + g], c,
                                   __ATOMIC_RELAXED, __HIP_MEMORY_SCOPE_AGENT);
            }
        }
        asm volatile("s_waitcnt vmcnt(0)" ::: "memory");
        __syncthreads();
        if (tid == 0)
            __hip_atomic_fetch_add(&syncs[4096 + 32 * (bid / PTILES)], 1,
                                   __ATOMIC_RELAXED, __HIP_MEMORY_SCOPE_AGENT);
    }

    // ================= phase A (blocks 0..511)
    if (bid < Q_TOT * PCHUNK) {
        const int q = bid & 31, c = bid >> 5;
        const int b0 = c * PTILES;
        int b1 = b0 + PTILES; if (b1 > NBLK3) b1 = NBLK3;
        if (tid == 0) {
            int* tc = &syncs[4096 + 32 * c];
            const int tgt = b1 - b0;
            while (__hip_atomic_load(tc, __ATOMIC_RELAXED, __HIP_MEMORY_SCOPE_AGENT) < tgt)
                __builtin_amdgcn_s_sleep(4);
        }
        __syncthreads();
        const int bq = tid >> 6, g = tid & 63;
        float acc = 0.f; int cacc = 0;
        for (int b = b0 + bq; b < b1; b += 4) {
            acc  += grp_part[b * (Q_TOT * G_TOT) + q * G_TOT + g];
            cacc += cnt_part[b * G_TOT + g];
        }
        ps[bq][g] = acc; pc[bq][g] = cacc;
        __syncthreads();
        if (tid < G_TOT) {
            const float s = ((ps[0][tid] + ps[1][tid]) + ps[2][tid]) + ps[3][tid];
            const int  cc = ((pc[0][tid] + pc[1][tid]) + pc[2][tid]) + pc[3][tid];
            __hip_atomic_store(&grp2[(c * Q_TOT + q) * G_TOT + tid], s,
                               __ATOMIC_RELAXED, __HIP_MEMORY_SCOPE_AGENT);
            __hip_atomic_store(&cnt2[(c * Q_TOT + q) * G_TOT + tid], cc,
                               __ATOMIC_RELAXED, __HIP_MEMORY_SCOPE_AGENT);
        }
        __shared__ int myturn;
        asm volatile("s_waitcnt vmcnt(0)" ::: "memory");
        if (tid == 0) {
            const int old = __hip_atomic_fetch_add(&syncs[3072 + 32 * q], 1,
                                                   __ATOMIC_RELAXED, __HIP_MEMORY_SCOPE_AGENT);
            myturn = (old == PCHUNK - 1) ? 1 : 0;
        }
        __syncthreads();
        if (myturn) {
            if (tid < G_TOT) {
                float s = 0.f; int cc = 0;
                #pragma unroll
                for (int c2 = 0; c2 < PCHUNK; ++c2) {
                    s  += grp2[(c2 * Q_TOT + q) * G_TOT + tid];
                    cc += cnt2[(c2 * Q_TOT + q) * G_TOT + tid];
                }
                sc[tid] = s / (float)cc;
            }
            __syncthreads();
            if (tid == 0) {
                float bv = sc[0]; int bi = 0;
                for (int g2 = 1; g2 < G_TOT; ++g2) if (sc[g2] > bv) { bv = sc[g2]; bi = g2; }
                __hip_atomic_store(&best[q], bi, __ATOMIC_RELAXED, __HIP_MEMORY_SCOPE_AGENT);
                asm volatile("s_waitcnt vmcnt(0)" ::: "memory");
                const int old = __hip_atomic_fetch_add(&syncs[5152 + 32], 1,
                                                       __ATOMIC_RELAXED, __HIP_MEMORY_SCOPE_AGENT);
                if (old == Q_TOT - 1) {
                    #pragma unroll
                    for (int f = 0; f < 8; ++f)
                        __hip_atomic_store(&syncs[4608 + 32 * f], 1,
                                           __ATOMIC_RELAXED, __HIP_MEMORY_SCOPE_AGENT);
                }
            }
        }
    }

    // ================= wait best-ready
    if (tid == 0) {
        int* fl = &syncs[4608 + 32 * (bid & 7)];
        while (__hip_atomic_load(fl, __ATOMIC_RELAXED, __HIP_MEMORY_SCOPE_AGENT) == 0)
            __builtin_amdgcn_s_sleep(16);
    }
    __syncthreads();

    if (tid < Q_TOT) bl[tid] = best[tid];
    __syncthreads();
    if (tid < G_TOT) {
        int m = 0;
        #pragma unroll
        for (int qq = 0; qq < Q_TOT; ++qq) m |= (bl[qq] == tid) ? (1 << qq) : 0;
        gm[tid] = m;
    }
    __syncthreads();

    // ================= phase O (line-spaced global accumulators, two-level exit ticket)
    {
        const int gidx = bid * 256 + tid;
        const int q4 = (gidx & 7) * 4;
        const int nstride = (TAIL_GRID * 256) >> 3;    // 32768
        int a0 = 0, a1 = 0, a2 = 0, a3 = 0;
        int u0 = 0, u1 = 0, u2 = 0, u3 = 0;
        for (int n = gidx >> 3; n < N_TOT; n += nstride) {
            const int m = gm[grps[supervox[n]]];
            const int4 g4 = *(const int4*)&gt[n * Q_TOT + q4];
            const int o0 = (m >> (q4 + 0)) & 1;
            const int o1 = (m >> (q4 + 1)) & 1;
            const int o2 = (m >> (q4 + 2)) & 1;
            const int o3 = (m >> (q4 + 3)) & 1;
            *(float4*)&out[n * Q_TOT + q4] =
                make_float4((float)o0, (float)o1, (float)o2, (float)o3);
            a0 += o0 & g4.x; u0 += o0 | g4.x;
            a1 += o1 & g4.y; u1 += o1 | g4.y;
            a2 += o2 & g4.z; u2 += o2 | g4.z;
            a3 += o3 & g4.w; u3 += o3 | g4.w;
        }
        if (tid < Q_TOT) { bi_s[tid] = 0; bu_s[tid] = 0; }
        __syncthreads();
        atomicAdd(&bi_s[q4 + 0], a0); atomicAdd(&bu_s[q4 + 0], u0);
        atomicAdd(&bi_s[q4 + 1], a1); atomicAdd(&bu_s[q4 + 1], u1);
        atomicAdd(&bi_s[q4 + 2], a2); atomicAdd(&bu_s[q4 + 2], u2);
        atomicAdd(&bi_s[q4 + 3], a3); atomicAdd(&bu_s[q4 + 3], u3);
        __syncthreads();
        if (tid < Q_TOT) {
            atomicAdd(&syncs[32 * tid], bi_s[tid]);            // interG line-spaced
            atomicAdd(&syncs[1024 + 32 * tid], bu_s[tid]);     // unionG line-spaced
        }
        asm volatile("s_waitcnt vmcnt(0)" ::: "memory");
        // two-level exit ticket: 8 sub-lines x 128, then top line x 8
        if (tid == 0) {
            islast = 0;
            const int sub = bid & 7;
            const int o1_ = __hip_atomic_fetch_add(&syncs[4864 + 32 * sub], 1,
                                                   __ATOMIC_RELAXED, __HIP_MEMORY_SCOPE_AGENT);
            if (o1_ == (TAIL_GRID / 8) - 1) {
                const int o2_ = __hip_atomic_fetch_add(&syncs[5152], 1,
                                                       __ATOMIC_RELAXED, __HIP_MEMORY_SCOPE_AGENT);
                islast = (o2_ == 7) ? 1 : 0;
            }
        }
        __syncthreads();
        if (islast && tid < Q_TOT) {
            const int iv = __hip_atomic_load(&syncs[32 * tid], __ATOMIC_RELAXED, __HIP_MEMORY_SCOPE_AGENT);
            const int uv = __hip_atomic_load(&syncs[1024 + 32 * tid], __ATOMIC_RELAXED, __HIP_MEMORY_SCOPE_AGENT);
            out[(size_t)N_TOT * Q_TOT + tid] = (float)iv / ((float)uv + 1e-5f);
        }
    }
}

extern "C" void kernel_launch(void* const* d_in, const int* in_sizes, int n_in,
                              void* d_out, int out_size, void* d_ws, size_t ws_size,
                              hipStream_t stream) {
    const float* lang_feat = (const float*)d_in[0];
    const float* feat      = (const float*)d_in[1];
    const float* coords    = (const float*)d_in[2];
    const int*   lang_len  = (const int*)d_in[3];
    const int*   grps      = (const int*)d_in[4];
    const int*   supervox  = (const int*)d_in[5];
    const int*   gt        = (const int*)d_in[6];
    const float* w_ih      = (const float*)d_in[7];
    const float* w_hh      = (const float*)d_in[8];
    const float* b_ih      = (const float*)d_in[9];
    const float* b_hh      = (const float*)d_in[10];
    const float* sqz_w1    = (const float*)d_in[11];
    const float* sqz_b1    = (const float*)d_in[12];
    const float* sqz_w2    = (const float*)d_in[13];
    const float* sqz_b2    = (const float*)d_in[14];
    const float* fuse_w    = (const float*)d_in[15];
    const float* fuse_b    = (const float*)d_in[16];
    const float* heat_w    = (const float*)d_in[17];
    const float* heat_b    = (const float*)d_in[18];
    float* out = (float*)d_out;

    float* gi       = (float*)d_ws;                       // 737280
    float* hbuf     = gi + 737280;                        // 8192
    float* langc    = hbuf + 8192;                        // 4096
    float* grp_part = langc + 4096;                       // 1280000
    int*   cnt_part = (int*)(grp_part + NBLK3 * 2048);    // 40000
    int*   best     = cnt_part + NBLK3 * 64;              // 32
    int*   syncs    = best + 32;                          // SYNCS_N
    float* hg       = (float*)(syncs + SYNCS_N);          // 245760
    float* fwt      = hg + HG_ELEMS;                      // 16768
    float* w1t      = fwt + FW_LD * D_FUSE;               // 16384
    float* w2t      = w1t + H_DIM * D_LANG;               // 4096
    float* wdr      = w2t + D_LANG * D_LANG;              // 128
    float* grp2     = wdr + 128;                          // 32768
    int*   cnt2     = (int*)(grp2 + PCHUNK * Q_TOT * G_TOT); // 32768

    k_gi   <<<GI_GRID + 9, 128, 0, stream>>>(lang_feat, w_ih, b_ih, fuse_w, sqz_w1, sqz_w2, heat_w,
                                             gi, fwt, w1t, w2t, wdr, hg, syncs);
    k_gru8 <<<Q_TOT * 8, 384, 0, stream>>>(gi, w_hh, b_hh, lang_len, hg, hbuf,
                                           w1t, sqz_b1, w2t, sqz_b2, fwt, fuse_b, langc,
                                           syncs + 2048);
    k_tail <<<TAIL_GRID, 256, 0, stream>>>(feat, coords, grps, langc, fwt, wdr, heat_b,
                                           grp_part, cnt_part, grp2, cnt2, best,
                                           supervox, gt, out, syncs);
}